// Round 6
// baseline (718.399 us; speedup 1.0000x reference)
//
#include <hip/hip_runtime.h>
#include <hip/hip_bf16.h>
#include <math.h>

// ---------------------------------------------------------------------------
// 3-layer GCN (PyG GCNConv, no self loops).
// R6: agg-first restructure. A(XW) = (AX)W, so each layer is now
//   g = A * act   (pure gather-sum aggregation)
//   h = ELU(g W + b)   (split-bf16 MFMA GEMM, bias+ELU fused in epilogue)
// Layer 1's aggregation then runs on the 64-dim input x (154 MB logical
// gather vs 614 MB in 256-dim; x is 26 MB ~ L2-resident) -> ~5x cheaper.
// GEMM structure unchanged from R5 (fragment-major packed B, dbuf
// global_load_lds staging, 2-phase pipeline, BM=128/BN=256/BK=32).
// Numerics: x*w ~ hi*wh + hi*wl + lo*wh (split-bf16, 3 MFMA planes).
// ---------------------------------------------------------------------------

#define THREADS 256

typedef __attribute__((ext_vector_type(8))) short short8;
typedef __attribute__((ext_vector_type(4))) float f32x4;

__global__ void k_deg(const int* __restrict__ dst, int* __restrict__ deg, int E) {
    int e = blockIdx.x * THREADS + threadIdx.x;
    if (e < E) atomicAdd(&deg[dst[e]], 1);
}

__global__ void k_dinv(const int* __restrict__ deg, float* __restrict__ dinv, int N) {
    int i = blockIdx.x * THREADS + threadIdx.x;
    if (i < N) {
        int d = deg[i];
        dinv[i] = (d > 0) ? rsqrtf((float)d) : 0.0f;
    }
}

__global__ void k_scan1(const int* __restrict__ deg, int* __restrict__ rowp,
                        int* __restrict__ bsums, int N) {
    __shared__ int s[THREADS];
    int idx = blockIdx.x * THREADS + threadIdx.x;
    int v = (idx < N) ? deg[idx] : 0;
    s[threadIdx.x] = v;
    __syncthreads();
    for (int off = 1; off < THREADS; off <<= 1) {
        int t = (threadIdx.x >= off) ? s[threadIdx.x - off] : 0;
        __syncthreads();
        s[threadIdx.x] += t;
        __syncthreads();
    }
    if (idx < N) rowp[idx] = s[threadIdx.x] - v;   // exclusive
    if (threadIdx.x == THREADS - 1) bsums[blockIdx.x] = s[threadIdx.x];
}

__global__ void k_scan2(int* __restrict__ bsums, int NB) {
    __shared__ int s[512];
    int v = (threadIdx.x < (unsigned)NB) ? bsums[threadIdx.x] : 0;
    s[threadIdx.x] = v;
    __syncthreads();
    for (int off = 1; off < 512; off <<= 1) {
        int t = (threadIdx.x >= (unsigned)off) ? s[threadIdx.x - off] : 0;
        __syncthreads();
        s[threadIdx.x] += t;
        __syncthreads();
    }
    if (threadIdx.x < (unsigned)NB) bsums[threadIdx.x] = s[threadIdx.x] - v;  // exclusive
}

__global__ void k_scan3(int* __restrict__ rowp, const int* __restrict__ bsums, int N) {
    int idx = blockIdx.x * THREADS + threadIdx.x;
    if (idx < N) rowp[idx] += bsums[blockIdx.x];
}

__global__ void k_fill(const int* __restrict__ src, const int* __restrict__ dst,
                       const float* __restrict__ dinv, const int* __restrict__ rowp,
                       int* __restrict__ cnt, int* __restrict__ esrc,
                       float* __restrict__ enorm, int E) {
    int e = blockIdx.x * THREADS + threadIdx.x;
    if (e >= E) return;
    int s = src[e], d = dst[e];
    int pos = rowp[d] + atomicAdd(&cnt[d], 1);
    esrc[pos]  = s;
    enorm[pos] = dinv[s] * dinv[d];
}

// ---- bf16 split helpers (round-to-nearest-even) ----
__device__ __forceinline__ unsigned bf16rn(float x) {
    unsigned u = __float_as_uint(x);
    return (u + 0x7FFFu + ((u >> 16) & 1u)) >> 16;
}
__device__ __forceinline__ void split1(float x, short8& h, short8& l, int e) {
    unsigned hb = bf16rn(x);
    float hf = __uint_as_float(hb << 16);
    h[e] = (short)hb;
    l[e] = (short)bf16rn(x - hf);
}
__device__ __forceinline__ void split4(float4 v, short8& h, short8& l, int e0) {
    split1(v.x, h, l, e0 + 0);
    split1(v.y, h, l, e0 + 1);
    split1(v.z, h, l, e0 + 2);
    split1(v.w, h, l, e0 + 3);
}

// W[K,256] -> Bpack fragment-major:
// frag index fr = (t*16+ct)*2+plane ; element = Bpack[fr*512 + lane*8 + e]
// where lane = kb*16 + r ; value = split(W[t*32+kb*8+e][ct*16+r])
__global__ void k_wsplit2(const float* __restrict__ W, short* __restrict__ Bp, int K) {
    int idx = blockIdx.x * THREADS + threadIdx.x;
    if (idx >= K * 256) return;
    int k = idx >> 8;
    int c = idx & 255;
    int t = k >> 5, kb = (k >> 3) & 3, e = k & 7;
    int ct = c >> 4, r = c & 15;
    float w = W[(size_t)k * 256 + c];
    unsigned hb = bf16rn(w);
    float hf = __uint_as_float(hb << 16);
    size_t base = ((size_t)(t * 16 + ct) * 2) * 512 + (kb * 16 + r) * 8 + e;
    Bp[base]       = (short)hb;
    Bp[base + 512] = (short)bf16rn(w - hf);
}

__device__ __forceinline__ void load_lds16(const void* g, void* l) {
    __builtin_amdgcn_global_load_lds(
        (const __attribute__((address_space(1))) void*)g,
        (__attribute__((address_space(3))) void*)l, 16, 0, 0);
}

__device__ __forceinline__ float elu1(float x) {
    return x > 0.0f ? x : expm1f(x);
}

// C[N,256] = ELU(act[N,K] @ W[K,256] + bias) via split-bf16 MFMA.
// Block = 256 threads = 4 waves. BM=128 (wave owns 32 rows: groups g0,g1 of
// 16), BN=256 (16 col-tiles), BK=32 per step. B staged in LDS (dbuf).
template <int K>
__global__ __launch_bounds__(256) void k_mgemm(const float* __restrict__ act,
                                               const short* __restrict__ Bpack,
                                               const float* __restrict__ bias,
                                               float* __restrict__ C, int N) {
    constexpr int NT = K / 32;
    __shared__ short Blds[2 * 16384];   // 2 x 32KB

    const int tid  = threadIdx.x;
    const int lane = tid & 63;
    const int wv   = tid >> 6;
    const int r    = lane & 15;
    const int kb   = lane >> 4;
    const int row0 = blockIdx.x * 128 + wv * 32;

    int ra = row0 + r;       if (ra >= N) ra = N - 1;
    int rb = row0 + 16 + r;  if (rb >= N) rb = N - 1;
    const float* apa = act + (size_t)ra * K + kb * 8;
    const float* apb = act + (size_t)rb * K + kb * 8;

    f32x4 acc0[16], acc1[16];
#pragma unroll
    for (int ct = 0; ct < 16; ++ct) { acc0[ct] = (f32x4)0.0f; acc1[ct] = (f32x4)0.0f; }

    // prologue: stage t=0, load raw A(0)
#pragma unroll
    for (int it = 0; it < 8; ++it)
        load_lds16(Bpack + it * 2048 + wv * 512 + lane * 8,
                   Blds + it * 2048 + wv * 512);
    float4 c00 = *(const float4*)(apa);
    float4 c01 = *(const float4*)(apa + 4);
    float4 c10 = *(const float4*)(apb);
    float4 c11 = *(const float4*)(apb + 4);
    __syncthreads();

    int cur = 0;
#pragma unroll 1
    for (int t = 0; t < NT; ++t) {
        float4 n00, n01, n10, n11;
        if (t + 1 < NT) {
            // stage B(t+1) into other buffer; prefetch raw A(t+1)
            const short* src = Bpack + (size_t)(t + 1) * 16384;
            short* dst = Blds + (cur ^ 1) * 16384;
#pragma unroll
            for (int it = 0; it < 8; ++it)
                load_lds16(src + it * 2048 + wv * 512 + lane * 8,
                           dst + it * 2048 + wv * 512);
            n00 = *(const float4*)(apa + (t + 1) * 32);
            n01 = *(const float4*)(apa + (t + 1) * 32 + 4);
            n10 = *(const float4*)(apb + (t + 1) * 32);
            n11 = *(const float4*)(apb + (t + 1) * 32 + 4);
        }

        // split current raw A into bf16 hi/lo fragments
        short8 ah0, al0, ah1, al1;
        split4(c00, ah0, al0, 0); split4(c01, ah0, al0, 4);
        split4(c10, ah1, al1, 0); split4(c11, ah1, al1, 4);

        const short* bb = Blds + cur * 16384;
#pragma unroll
        for (int ct = 0; ct < 16; ++ct) {
            short8 bh = *(const short8*)(bb + (ct * 2 + 0) * 512 + lane * 8);
            short8 bl = *(const short8*)(bb + (ct * 2 + 1) * 512 + lane * 8);
            acc0[ct] = __builtin_amdgcn_mfma_f32_16x16x32_bf16(ah0, bh, acc0[ct], 0, 0, 0);
            acc0[ct] = __builtin_amdgcn_mfma_f32_16x16x32_bf16(ah0, bl, acc0[ct], 0, 0, 0);
            acc0[ct] = __builtin_amdgcn_mfma_f32_16x16x32_bf16(al0, bh, acc0[ct], 0, 0, 0);
            acc1[ct] = __builtin_amdgcn_mfma_f32_16x16x32_bf16(ah1, bh, acc1[ct], 0, 0, 0);
            acc1[ct] = __builtin_amdgcn_mfma_f32_16x16x32_bf16(ah1, bl, acc1[ct], 0, 0, 0);
            acc1[ct] = __builtin_amdgcn_mfma_f32_16x16x32_bf16(al1, bh, acc1[ct], 0, 0, 0);
        }
        __syncthreads();   // drains stage(t+1) vmcnt; waves done reading cur

        if (t + 1 < NT) { c00 = n00; c01 = n01; c10 = n10; c11 = n11; }
        cur ^= 1;
    }

    // bias per output column ct*16 + r (static-indexed -> registers)
    float bv[16];
#pragma unroll
    for (int ct = 0; ct < 16; ++ct) bv[ct] = bias[ct * 16 + r];

    // C/D layout: row = 4*(lane>>4)+reg, col = lane&15 (within tile)
#pragma unroll
    for (int jr = 0; jr < 4; ++jr) {
        int g0 = row0 + kb * 4 + jr;
        if (g0 < N) {
            float* cp = C + (size_t)g0 * 256 + r;
#pragma unroll
            for (int ct = 0; ct < 16; ++ct) cp[ct * 16] = elu1(acc0[ct][jr] + bv[ct]);
        }
        int g1 = row0 + 16 + kb * 4 + jr;
        if (g1 < N) {
            float* cp = C + (size_t)g1 * 256 + r;
#pragma unroll
            for (int ct = 0; ct < 16; ++ct) cp[ct * 16] = elu1(acc1[ct][jr] + bv[ct]);
        }
    }
}

// pure aggregation, 256-dim: g[node] = sum norm * h[src]. One wave per node,
// lane owns 4 channels. 2-way unrolled edge loop.
__global__ __launch_bounds__(256) void k_aggp(const float* __restrict__ h,
                                              const int* __restrict__ rowp,
                                              const int* __restrict__ deg,
                                              const int* __restrict__ esrc,
                                              const float* __restrict__ enorm,
                                              float* __restrict__ g, int N) {
    int wave = threadIdx.x >> 6;
    int lane = threadIdx.x & 63;
    int node = blockIdx.x * 4 + wave;
    if (node >= N) return;

    int start = rowp[node];
    int cnt   = deg[node];

    float4 acc = make_float4(0.f, 0.f, 0.f, 0.f);
    float4 acc2 = make_float4(0.f, 0.f, 0.f, 0.f);
    int e = 0;
    for (; e + 2 <= cnt; e += 2) {
        int   s0 = esrc[start + e];
        int   s1 = esrc[start + e + 1];
        float n0 = enorm[start + e];
        float n1 = enorm[start + e + 1];
        float4 h0 = *(const float4*)&h[(size_t)s0 * 256 + lane * 4];
        float4 h1 = *(const float4*)&h[(size_t)s1 * 256 + lane * 4];
        acc.x += n0 * h0.x;  acc.y += n0 * h0.y;
        acc.z += n0 * h0.z;  acc.w += n0 * h0.w;
        acc2.x += n1 * h1.x; acc2.y += n1 * h1.y;
        acc2.z += n1 * h1.z; acc2.w += n1 * h1.w;
    }
    if (e < cnt) {
        int   s0 = esrc[start + e];
        float n0 = enorm[start + e];
        float4 h0 = *(const float4*)&h[(size_t)s0 * 256 + lane * 4];
        acc.x += n0 * h0.x; acc.y += n0 * h0.y;
        acc.z += n0 * h0.z; acc.w += n0 * h0.w;
    }
    float4 o;
    o.x = acc.x + acc2.x; o.y = acc.y + acc2.y;
    o.z = acc.z + acc2.z; o.w = acc.w + acc2.w;
    *(float4*)&g[(size_t)node * 256 + lane * 4] = o;
}

// pure aggregation, 64-dim input: g[node][c] = sum norm * x[src][c].
// One wave per node, lane owns 1 channel (4B x 64 lanes = 256B row).
__global__ __launch_bounds__(256) void k_agg64(const float* __restrict__ x,
                                               const int* __restrict__ rowp,
                                               const int* __restrict__ deg,
                                               const int* __restrict__ esrc,
                                               const float* __restrict__ enorm,
                                               float* __restrict__ g, int N) {
    int wave = threadIdx.x >> 6;
    int lane = threadIdx.x & 63;
    int node = blockIdx.x * 4 + wave;
    if (node >= N) return;

    int start = rowp[node];
    int cnt   = deg[node];

    float a0 = 0.f, a1 = 0.f;
    int e = 0;
    for (; e + 2 <= cnt; e += 2) {
        int   s0 = esrc[start + e];
        int   s1 = esrc[start + e + 1];
        float n0 = enorm[start + e];
        float n1 = enorm[start + e + 1];
        a0 += n0 * x[(size_t)s0 * 64 + lane];
        a1 += n1 * x[(size_t)s1 * 64 + lane];
    }
    if (e < cnt) {
        int s0 = esrc[start + e];
        a0 += enorm[start + e] * x[(size_t)s0 * 64 + lane];
    }
    g[(size_t)node * 64 + lane] = a0 + a1;
}

static inline size_t alignup(size_t x) { return (x + 255) & ~(size_t)255; }

extern "C" void kernel_launch(void* const* d_in, const int* in_sizes, int n_in,
                              void* d_out, int out_size, void* d_ws, size_t ws_size,
                              hipStream_t stream) {
    const float* x  = (const float*)d_in[0];
    const int*   ei = (const int*)d_in[1];
    const float* W1 = (const float*)d_in[2];
    const float* b1 = (const float*)d_in[3];
    const float* W2 = (const float*)d_in[4];
    const float* b2 = (const float*)d_in[5];
    const float* W3 = (const float*)d_in[6];
    const float* b3 = (const float*)d_in[7];
    float* out = (float*)d_out;

    const int N = in_sizes[0] / 64;   // 100000
    const int E = in_sizes[1] / 2;    // 600000
    const int* src = ei;
    const int* dst = ei + E;

    // workspace carve (deg,cnt adjacent -> one memset)
    char* p = (char*)d_ws;
    int*   deg   = (int*)p;   p += alignup((size_t)N * 4);
    int*   cnt   = (int*)p;   p += alignup((size_t)N * 4);
    float* dinv  = (float*)p; p += alignup((size_t)N * 4);
    int*   rowp  = (int*)p;   p += alignup((size_t)N * 4);
    int*   esrc  = (int*)p;   p += alignup((size_t)E * 4);
    float* enorm = (float*)p; p += alignup((size_t)E * 4);
    const int NB = (N + THREADS - 1) / THREADS;
    int*   bsums = (int*)p;   p += alignup((size_t)NB * 4);
    short* Bpack = (short*)p; p += alignup((size_t)256 * 256 * 2 * 2); // 256KB max
    float* G     = (float*)p; p += alignup((size_t)N * 256 * 4);       // agg output

    const int EB = (E + THREADS - 1) / THREADS;
    const int GB = (N + 127) / 128;     // gemm blocks (128 rows each)
    const int AB = (N + 3) / 4;         // agg blocks (4 waves/block)

    hipMemsetAsync(deg, 0, alignup((size_t)N * 4) + (size_t)N * 4, stream);

    k_deg<<<EB, THREADS, 0, stream>>>(dst, deg, E);
    k_dinv<<<NB, THREADS, 0, stream>>>(deg, dinv, N);
    k_scan1<<<NB, THREADS, 0, stream>>>(deg, rowp, bsums, N);
    k_scan2<<<1, 512, 0, stream>>>(bsums, NB);
    k_scan3<<<NB, THREADS, 0, stream>>>(rowp, bsums, N);
    k_fill<<<EB, THREADS, 0, stream>>>(src, dst, dinv, rowp, cnt, esrc, enorm, E);

    // layer 1: g1 = A x (64-dim); h1 = ELU(g1 W1 + b1) -> d_out
    k_agg64<<<AB, THREADS, 0, stream>>>(x, rowp, deg, esrc, enorm, G, N);
    k_wsplit2<<<(64 * 256 + THREADS - 1) / THREADS, THREADS, 0, stream>>>(W1, Bpack, 64);
    k_mgemm<64><<<GB, THREADS, 0, stream>>>(G, Bpack, b1, out, N);

    // layer 2: g2 = A h1; h2 = ELU(g2 W2 + b2) -> d_out
    k_aggp<<<AB, THREADS, 0, stream>>>(out, rowp, deg, esrc, enorm, G, N);
    k_wsplit2<<<(256 * 256 + THREADS - 1) / THREADS, THREADS, 0, stream>>>(W2, Bpack, 256);
    k_mgemm<256><<<GB, THREADS, 0, stream>>>(G, Bpack, b2, out, N);

    // layer 3: g3 = A h2; h3 = ELU(g3 W3 + b3) -> d_out
    k_aggp<<<AB, THREADS, 0, stream>>>(out, rowp, deg, esrc, enorm, G, N);
    k_wsplit2<<<(256 * 256 + THREADS - 1) / THREADS, THREADS, 0, stream>>>(W3, Bpack, 256);
    k_mgemm<256><<<GB, THREADS, 0, stream>>>(G, Bpack, b3, out, N);
}

// Round 9
// 572.577 us; speedup vs baseline: 1.2547x; 1.2547x over previous
//
#include <hip/hip_runtime.h>
#include <hip/hip_bf16.h>
#include <math.h>

// ---------------------------------------------------------------------------
// 3-layer GCN (PyG GCNConv, no self loops), agg-first form:
//   g = A * act (gather-sum) ; h = ELU(g W + b) (split-bf16 MFMA GEMM)
// R8 (resubmit; R8 bench never acquired a GPU): R7's single-buffer staging
// had a 4x offset bug ((wv*8+it)*2048 instead of *512): OOB LDS writes +
// 3/4 of B-tile uninitialized -> NaN. Fixed.
// Structure: BM=64/block (acc[16] = 64 VGPRs, peak ~106 live, bounds(256,4)
// -> 4 blocks/CU), single 32KB LDS B-tile, 2 barriers/k-step, fast ELU,
// 4-way independent-acc agg unroll.
// Numerics: x*w ~ hi*wh + hi*wl + lo*wh (split-bf16, 3 MFMA planes).
// ---------------------------------------------------------------------------

#define THREADS 256

typedef __attribute__((ext_vector_type(8))) short short8;
typedef __attribute__((ext_vector_type(4))) float f32x4;

__global__ void k_deg(const int* __restrict__ dst, int* __restrict__ deg, int E) {
    int e = blockIdx.x * THREADS + threadIdx.x;
    if (e < E) atomicAdd(&deg[dst[e]], 1);
}

__global__ void k_dinv(const int* __restrict__ deg, float* __restrict__ dinv, int N) {
    int i = blockIdx.x * THREADS + threadIdx.x;
    if (i < N) {
        int d = deg[i];
        dinv[i] = (d > 0) ? rsqrtf((float)d) : 0.0f;
    }
}

__global__ void k_scan1(const int* __restrict__ deg, int* __restrict__ rowp,
                        int* __restrict__ bsums, int N) {
    __shared__ int s[THREADS];
    int idx = blockIdx.x * THREADS + threadIdx.x;
    int v = (idx < N) ? deg[idx] : 0;
    s[threadIdx.x] = v;
    __syncthreads();
    for (int off = 1; off < THREADS; off <<= 1) {
        int t = (threadIdx.x >= off) ? s[threadIdx.x - off] : 0;
        __syncthreads();
        s[threadIdx.x] += t;
        __syncthreads();
    }
    if (idx < N) rowp[idx] = s[threadIdx.x] - v;   // exclusive
    if (threadIdx.x == THREADS - 1) bsums[blockIdx.x] = s[threadIdx.x];
}

__global__ void k_scan2(int* __restrict__ bsums, int NB) {
    __shared__ int s[512];
    int v = (threadIdx.x < (unsigned)NB) ? bsums[threadIdx.x] : 0;
    s[threadIdx.x] = v;
    __syncthreads();
    for (int off = 1; off < 512; off <<= 1) {
        int t = (threadIdx.x >= (unsigned)off) ? s[threadIdx.x - off] : 0;
        __syncthreads();
        s[threadIdx.x] += t;
        __syncthreads();
    }
    if (threadIdx.x < (unsigned)NB) bsums[threadIdx.x] = s[threadIdx.x] - v;  // exclusive
}

__global__ void k_scan3(int* __restrict__ rowp, const int* __restrict__ bsums, int N) {
    int idx = blockIdx.x * THREADS + threadIdx.x;
    if (idx < N) rowp[idx] += bsums[blockIdx.x];
}

__global__ void k_fill(const int* __restrict__ src, const int* __restrict__ dst,
                       const float* __restrict__ dinv, const int* __restrict__ rowp,
                       int* __restrict__ cnt, int* __restrict__ esrc,
                       float* __restrict__ enorm, int E) {
    int e = blockIdx.x * THREADS + threadIdx.x;
    if (e >= E) return;
    int s = src[e], d = dst[e];
    int pos = rowp[d] + atomicAdd(&cnt[d], 1);
    esrc[pos]  = s;
    enorm[pos] = dinv[s] * dinv[d];
}

// ---- bf16 split helpers (round-to-nearest-even) ----
__device__ __forceinline__ unsigned bf16rn(float x) {
    unsigned u = __float_as_uint(x);
    return (u + 0x7FFFu + ((u >> 16) & 1u)) >> 16;
}
__device__ __forceinline__ void split1(float x, short8& h, short8& l, int e) {
    unsigned hb = bf16rn(x);
    float hf = __uint_as_float(hb << 16);
    h[e] = (short)hb;
    l[e] = (short)bf16rn(x - hf);
}
__device__ __forceinline__ void split4(float4 v, short8& h, short8& l, int e0) {
    split1(v.x, h, l, e0 + 0);
    split1(v.y, h, l, e0 + 1);
    split1(v.z, h, l, e0 + 2);
    split1(v.w, h, l, e0 + 3);
}

// W[K,256] -> Bpack fragment-major:
// frag index fr = (t*16+ct)*2+plane ; element = Bpack[fr*512 + lane*8 + e]
// where lane = kb*16 + r ; value = split(W[t*32+kb*8+e][ct*16+r])
__global__ void k_wsplit2(const float* __restrict__ W, short* __restrict__ Bp, int K) {
    int idx = blockIdx.x * THREADS + threadIdx.x;
    if (idx >= K * 256) return;
    int k = idx >> 8;
    int c = idx & 255;
    int t = k >> 5, kb = (k >> 3) & 3, e = k & 7;
    int ct = c >> 4, r = c & 15;
    float w = W[(size_t)k * 256 + c];
    unsigned hb = bf16rn(w);
    float hf = __uint_as_float(hb << 16);
    size_t base = ((size_t)(t * 16 + ct) * 2) * 512 + (kb * 16 + r) * 8 + e;
    Bp[base]       = (short)hb;
    Bp[base + 512] = (short)bf16rn(w - hf);
}

__device__ __forceinline__ void load_lds16(const void* g, void* l) {
    __builtin_amdgcn_global_load_lds(
        (const __attribute__((address_space(1))) void*)g,
        (__attribute__((address_space(3))) void*)l, 16, 0, 0);
}

__device__ __forceinline__ float elu_fast(float x) {
    return x > 0.0f ? x : (__expf(x) - 1.0f);
}

// C[N,256] = ELU(act[N,K] @ W[K,256] + bias) via split-bf16 MFMA.
// Block = 256 threads = 4 waves; each wave computes 16 rows x 256 cols.
// Single 32KB LDS buffer for B(t): 32 fragments x 512 shorts (1KB each);
// wave wv stages fragments wv*8..wv*8+7. 2 barriers per k-step; 4 blocks/CU.
template <int K>
__global__ __launch_bounds__(256, 4) void k_mgemm(const float* __restrict__ act,
                                                  const short* __restrict__ Bpack,
                                                  const float* __restrict__ bias,
                                                  float* __restrict__ C, int N) {
    constexpr int NT = K / 32;
    __shared__ short Blds[16384];   // 32 KB: one B k-tile (16 ct x 2 planes x 512)

    const int tid  = threadIdx.x;
    const int lane = tid & 63;
    const int wv   = tid >> 6;
    const int r    = lane & 15;
    const int kb   = lane >> 4;
    const int row0 = blockIdx.x * 64 + wv * 16;

    int ra = row0 + r;
    if (ra >= N) ra = N - 1;        // clamp; junk rows never written
    const float* ap = act + (size_t)ra * K + kb * 8;

    f32x4 acc[16];
#pragma unroll
    for (int ct = 0; ct < 16; ++ct) acc[ct] = (f32x4)0.0f;

    // A(0)
    float4 c0 = *(const float4*)(ap);
    float4 c1 = *(const float4*)(ap + 4);

#pragma unroll 1
    for (int t = 0; t < NT; ++t) {
        // stage B(t): 32 fragments x 1KB; wave wv stages fragments wv*8+it
        const short* bsrc = Bpack + (size_t)t * 16384;
#pragma unroll
        for (int it = 0; it < 8; ++it)
            load_lds16(bsrc + (wv * 8 + it) * 512 + lane * 8,
                       Blds + (wv * 8 + it) * 512);
        // prefetch raw A(t+1)
        float4 n0, n1;
        if (t + 1 < NT) {
            n0 = *(const float4*)(ap + (t + 1) * 32);
            n1 = *(const float4*)(ap + (t + 1) * 32 + 4);
        }
        __syncthreads();   // B(t) staged (drains vmcnt)

        short8 ah, al;
        split4(c0, ah, al, 0); split4(c1, ah, al, 4);

#pragma unroll
        for (int ct = 0; ct < 16; ++ct) {
            short8 bh = *(const short8*)(Blds + (ct * 2 + 0) * 512 + lane * 8);
            short8 bl = *(const short8*)(Blds + (ct * 2 + 1) * 512 + lane * 8);
            acc[ct] = __builtin_amdgcn_mfma_f32_16x16x32_bf16(ah, bh, acc[ct], 0, 0, 0);
            acc[ct] = __builtin_amdgcn_mfma_f32_16x16x32_bf16(ah, bl, acc[ct], 0, 0, 0);
            acc[ct] = __builtin_amdgcn_mfma_f32_16x16x32_bf16(al, bh, acc[ct], 0, 0, 0);
        }
        __syncthreads();   // all waves done reading B(t) before next stage

        if (t + 1 < NT) { c0 = n0; c1 = n1; }
    }

    // bias per output column ct*16 + r (static-indexed -> registers)
    float bv[16];
#pragma unroll
    for (int ct = 0; ct < 16; ++ct) bv[ct] = bias[ct * 16 + r];

    // C/D layout: row = 4*(lane>>4)+reg, col = lane&15 (within tile)
#pragma unroll
    for (int jr = 0; jr < 4; ++jr) {
        int gr = row0 + kb * 4 + jr;
        if (gr < N) {
            float* cp = C + (size_t)gr * 256 + r;
#pragma unroll
            for (int ct = 0; ct < 16; ++ct) cp[ct * 16] = elu_fast(acc[ct][jr] + bv[ct]);
        }
    }
}

// pure aggregation, 256-dim: g[node] = sum norm * h[src]. One wave per node,
// lane owns 4 channels. 4-way independent-accumulator unroll.
__global__ __launch_bounds__(256) void k_aggp(const float* __restrict__ h,
                                              const int* __restrict__ rowp,
                                              const int* __restrict__ deg,
                                              const int* __restrict__ esrc,
                                              const float* __restrict__ enorm,
                                              float* __restrict__ g, int N) {
    int wave = threadIdx.x >> 6;
    int lane = threadIdx.x & 63;
    int node = blockIdx.x * 4 + wave;
    if (node >= N) return;

    int start = rowp[node];
    int cnt   = deg[node];

    float4 a0 = make_float4(0.f, 0.f, 0.f, 0.f);
    float4 a1 = make_float4(0.f, 0.f, 0.f, 0.f);
    float4 a2 = make_float4(0.f, 0.f, 0.f, 0.f);
    float4 a3 = make_float4(0.f, 0.f, 0.f, 0.f);
    int e = 0;
    for (; e + 4 <= cnt; e += 4) {
        int   s0 = esrc[start + e + 0];
        int   s1 = esrc[start + e + 1];
        int   s2 = esrc[start + e + 2];
        int   s3 = esrc[start + e + 3];
        float n0 = enorm[start + e + 0];
        float n1 = enorm[start + e + 1];
        float n2 = enorm[start + e + 2];
        float n3 = enorm[start + e + 3];
        float4 h0 = *(const float4*)&h[(size_t)s0 * 256 + lane * 4];
        float4 h1 = *(const float4*)&h[(size_t)s1 * 256 + lane * 4];
        float4 h2 = *(const float4*)&h[(size_t)s2 * 256 + lane * 4];
        float4 h3 = *(const float4*)&h[(size_t)s3 * 256 + lane * 4];
        a0.x += n0 * h0.x; a0.y += n0 * h0.y; a0.z += n0 * h0.z; a0.w += n0 * h0.w;
        a1.x += n1 * h1.x; a1.y += n1 * h1.y; a1.z += n1 * h1.z; a1.w += n1 * h1.w;
        a2.x += n2 * h2.x; a2.y += n2 * h2.y; a2.z += n2 * h2.z; a2.w += n2 * h2.w;
        a3.x += n3 * h3.x; a3.y += n3 * h3.y; a3.z += n3 * h3.z; a3.w += n3 * h3.w;
    }
    for (; e < cnt; ++e) {
        int   s0 = esrc[start + e];
        float n0 = enorm[start + e];
        float4 h0 = *(const float4*)&h[(size_t)s0 * 256 + lane * 4];
        a0.x += n0 * h0.x; a0.y += n0 * h0.y; a0.z += n0 * h0.z; a0.w += n0 * h0.w;
    }
    float4 o;
    o.x = (a0.x + a1.x) + (a2.x + a3.x);
    o.y = (a0.y + a1.y) + (a2.y + a3.y);
    o.z = (a0.z + a1.z) + (a2.z + a3.z);
    o.w = (a0.w + a1.w) + (a2.w + a3.w);
    *(float4*)&g[(size_t)node * 256 + lane * 4] = o;
}

// pure aggregation, 64-dim input: g[node][c] = sum norm * x[src][c].
// One wave per node, lane owns 1 channel. 4-way unroll.
__global__ __launch_bounds__(256) void k_agg64(const float* __restrict__ x,
                                               const int* __restrict__ rowp,
                                               const int* __restrict__ deg,
                                               const int* __restrict__ esrc,
                                               const float* __restrict__ enorm,
                                               float* __restrict__ g, int N) {
    int wave = threadIdx.x >> 6;
    int lane = threadIdx.x & 63;
    int node = blockIdx.x * 4 + wave;
    if (node >= N) return;

    int start = rowp[node];
    int cnt   = deg[node];

    float a0 = 0.f, a1 = 0.f, a2 = 0.f, a3 = 0.f;
    int e = 0;
    for (; e + 4 <= cnt; e += 4) {
        int   s0 = esrc[start + e + 0];
        int   s1 = esrc[start + e + 1];
        int   s2 = esrc[start + e + 2];
        int   s3 = esrc[start + e + 3];
        float n0 = enorm[start + e + 0];
        float n1 = enorm[start + e + 1];
        float n2 = enorm[start + e + 2];
        float n3 = enorm[start + e + 3];
        a0 += n0 * x[(size_t)s0 * 64 + lane];
        a1 += n1 * x[(size_t)s1 * 64 + lane];
        a2 += n2 * x[(size_t)s2 * 64 + lane];
        a3 += n3 * x[(size_t)s3 * 64 + lane];
    }
    for (; e < cnt; ++e) {
        int s0 = esrc[start + e];
        a0 += enorm[start + e] * x[(size_t)s0 * 64 + lane];
    }
    g[(size_t)node * 64 + lane] = (a0 + a1) + (a2 + a3);
}

static inline size_t alignup(size_t x) { return (x + 255) & ~(size_t)255; }

extern "C" void kernel_launch(void* const* d_in, const int* in_sizes, int n_in,
                              void* d_out, int out_size, void* d_ws, size_t ws_size,
                              hipStream_t stream) {
    const float* x  = (const float*)d_in[0];
    const int*   ei = (const int*)d_in[1];
    const float* W1 = (const float*)d_in[2];
    const float* b1 = (const float*)d_in[3];
    const float* W2 = (const float*)d_in[4];
    const float* b2 = (const float*)d_in[5];
    const float* W3 = (const float*)d_in[6];
    const float* b3 = (const float*)d_in[7];
    float* out = (float*)d_out;

    const int N = in_sizes[0] / 64;   // 100000
    const int E = in_sizes[1] / 2;    // 600000
    const int* src = ei;
    const int* dst = ei + E;

    // workspace carve (deg,cnt adjacent -> one memset)
    char* p = (char*)d_ws;
    int*   deg   = (int*)p;   p += alignup((size_t)N * 4);
    int*   cnt   = (int*)p;   p += alignup((size_t)N * 4);
    float* dinv  = (float*)p; p += alignup((size_t)N * 4);
    int*   rowp  = (int*)p;   p += alignup((size_t)N * 4);
    int*   esrc  = (int*)p;   p += alignup((size_t)E * 4);
    float* enorm = (float*)p; p += alignup((size_t)E * 4);
    const int NB = (N + THREADS - 1) / THREADS;
    int*   bsums = (int*)p;   p += alignup((size_t)NB * 4);
    short* Bpack = (short*)p; p += alignup((size_t)256 * 256 * 2 * 2); // 256KB max
    float* G     = (float*)p; p += alignup((size_t)N * 256 * 4);       // agg output

    const int EB = (E + THREADS - 1) / THREADS;
    const int GB = (N + 63) / 64;       // gemm blocks (64 rows each)
    const int AB = (N + 3) / 4;         // agg blocks (4 waves/block)

    hipMemsetAsync(deg, 0, alignup((size_t)N * 4) + (size_t)N * 4, stream);

    k_deg<<<EB, THREADS, 0, stream>>>(dst, deg, E);
    k_dinv<<<NB, THREADS, 0, stream>>>(deg, dinv, N);
    k_scan1<<<NB, THREADS, 0, stream>>>(deg, rowp, bsums, N);
    k_scan2<<<1, 512, 0, stream>>>(bsums, NB);
    k_scan3<<<NB, THREADS, 0, stream>>>(rowp, bsums, N);
    k_fill<<<EB, THREADS, 0, stream>>>(src, dst, dinv, rowp, cnt, esrc, enorm, E);

    // layer 1: g1 = A x (64-dim); h1 = ELU(g1 W1 + b1) -> d_out
    k_agg64<<<AB, THREADS, 0, stream>>>(x, rowp, deg, esrc, enorm, G, N);
    k_wsplit2<<<(64 * 256 + THREADS - 1) / THREADS, THREADS, 0, stream>>>(W1, Bpack, 64);
    k_mgemm<64><<<GB, THREADS, 0, stream>>>(G, Bpack, b1, out, N);

    // layer 2: g2 = A h1; h2 = ELU(g2 W2 + b2) -> d_out
    k_aggp<<<AB, THREADS, 0, stream>>>(out, rowp, deg, esrc, enorm, G, N);
    k_wsplit2<<<(256 * 256 + THREADS - 1) / THREADS, THREADS, 0, stream>>>(W2, Bpack, 256);
    k_mgemm<256><<<GB, THREADS, 0, stream>>>(G, Bpack, b2, out, N);

    // layer 3: g3 = A h2; h3 = ELU(g3 W3 + b3) -> d_out
    k_aggp<<<AB, THREADS, 0, stream>>>(out, rowp, deg, esrc, enorm, G, N);
    k_wsplit2<<<(256 * 256 + THREADS - 1) / THREADS, THREADS, 0, stream>>>(W3, Bpack, 256);
    k_mgemm<256><<<GB, THREADS, 0, stream>>>(G, Bpack, b3, out, N);
}